// Round 1
// baseline (1508.347 us; speedup 1.0000x reference)
//
#include <hip/hip_runtime.h>

#define N_NODES 50000
#define N_EDGES 800000
#define IN_DIM  128
#define HID_DIM 64
#define OUT_DIM 64

// ---------------- degree ----------------
__global__ void k_deg_init(float* __restrict__ deg) {
    int i = blockIdx.x * blockDim.x + threadIdx.x;
    if (i < N_NODES) deg[i] = 1.0f;  // self-loop contributes 1
}

__global__ void k_deg_count(const int* __restrict__ dst, float* __restrict__ deg) {
    int tid = blockIdx.x * blockDim.x + threadIdx.x;
    int stride = gridDim.x * blockDim.x;
    for (int e = tid; e < N_EDGES; e += stride)
        atomicAdd(&deg[dst[e]], 1.0f);
}

__global__ void k_dinv(float* __restrict__ deg) {
    int i = blockIdx.x * blockDim.x + threadIdx.x;
    if (i < N_NODES) deg[i] = rsqrtf(deg[i]);  // deg >= 1 always (self-loop)
}

// ---------------- GEMM1: h1 = x @ W1 ; out1 = h1*dinv^2 + b1 (self-loop + bias init) ----
__global__ __launch_bounds__(256) void k_gemm1(
        const float* __restrict__ x, const float* __restrict__ W1,
        const float* __restrict__ b1, const float* __restrict__ dinv,
        float* __restrict__ h1, float* __restrict__ out1) {
    __shared__ float xs[4][IN_DIM];
    const int wave = threadIdx.x >> 6;
    const int lane = threadIdx.x & 63;
    const int n = blockIdx.x * 4 + wave;
    if (n < N_NODES) {
        xs[wave][lane]      = x[(long)n * IN_DIM + lane];
        xs[wave][lane + 64] = x[(long)n * IN_DIM + lane + 64];
    }
    __syncthreads();
    if (n >= N_NODES) return;
    float acc = 0.0f;
#pragma unroll 8
    for (int k = 0; k < IN_DIM; ++k)
        acc = fmaf(xs[wave][k], W1[k * HID_DIM + lane], acc);
    h1[(long)n * HID_DIM + lane] = acc;
    const float di = dinv[n];
    out1[(long)n * HID_DIM + lane] = acc * di * di + b1[lane];
}

// ---------------- edge aggregation: out[dst] += h[src] * dinv[src]*dinv[dst] ----------
__global__ __launch_bounds__(256) void k_agg(
        const int* __restrict__ src, const int* __restrict__ dst,
        const float* __restrict__ dinv, const float* __restrict__ h,
        float* __restrict__ out) {
    const long tid = (long)blockIdx.x * blockDim.x + threadIdx.x;
    const long stride = (long)gridDim.x * blockDim.x;
    const long total = (long)N_EDGES * 16;  // 16 float4 chunks per edge
    for (long item = tid; item < total; item += stride) {
        const int e = (int)(item >> 4);
        const int c = (int)(item & 15);
        const int s = src[e];
        const int d = dst[e];
        const float norm = dinv[s] * dinv[d];
        const float4 hv = *reinterpret_cast<const float4*>(&h[(long)s * 64 + c * 4]);
        float* o = &out[(long)d * 64 + c * 4];
        atomicAdd(o + 0, hv.x * norm);
        atomicAdd(o + 1, hv.y * norm);
        atomicAdd(o + 2, hv.z * norm);
        atomicAdd(o + 3, hv.w * norm);
    }
}

// ---------------- GEMM2: h2 = relu(out1); h3 = h2 @ W2 (in-place over out1);
//                  dout = h3*dinv^2 + b2 (self-loop + bias init) ----------------------
__global__ __launch_bounds__(256) void k_gemm2(
        const float* __restrict__ W2, const float* __restrict__ b2,
        const float* __restrict__ dinv,
        float* __restrict__ out1 /* in: agg1 result, out: h3 */,
        float* __restrict__ dout) {
    __shared__ float hs[4][HID_DIM];
    const int wave = threadIdx.x >> 6;
    const int lane = threadIdx.x & 63;
    const int n = blockIdx.x * 4 + wave;
    if (n < N_NODES)
        hs[wave][lane] = fmaxf(out1[(long)n * HID_DIM + lane], 0.0f);
    __syncthreads();
    if (n >= N_NODES) return;
    float acc = 0.0f;
#pragma unroll 8
    for (int k = 0; k < HID_DIM; ++k)
        acc = fmaf(hs[wave][k], W2[k * OUT_DIM + lane], acc);
    out1[(long)n * HID_DIM + lane] = acc;  // h3 overwrites out1 (own row only, already staged)
    const float di = dinv[n];
    dout[(long)n * OUT_DIM + lane] = acc * di * di + b2[lane];
}

extern "C" void kernel_launch(void* const* d_in, const int* in_sizes, int n_in,
                              void* d_out, int out_size, void* d_ws, size_t ws_size,
                              hipStream_t stream) {
    const float* x  = (const float*)d_in[0];
    const int*   ei = (const int*)d_in[1];          // [2, N_EDGES]
    const float* W1 = (const float*)d_in[2];
    const float* b1 = (const float*)d_in[3];
    const float* W2 = (const float*)d_in[4];
    const float* b2 = (const float*)d_in[5];
    float* dout = (float*)d_out;

    const int* src = ei;
    const int* dst = ei + N_EDGES;

    float* ws = (float*)d_ws;
    float* deg  = ws;                        // N_NODES, becomes dinv in place
    float* h1   = ws + 65536;                // N_NODES*64
    float* out1 = h1 + (long)N_NODES * 64;   // N_NODES*64 (becomes h3 in place)

    const int nb_nodes = (N_NODES + 255) / 256;

    k_deg_init<<<nb_nodes, 256, 0, stream>>>(deg);
    k_deg_count<<<2048, 256, 0, stream>>>(dst, deg);
    k_dinv<<<nb_nodes, 256, 0, stream>>>(deg);

    k_gemm1<<<(N_NODES + 3) / 4, 256, 0, stream>>>(x, W1, b1, deg, h1, out1);
    k_agg<<<2048, 256, 0, stream>>>(src, dst, deg, h1, out1);
    k_gemm2<<<(N_NODES + 3) / 4, 256, 0, stream>>>(W2, b2, deg, out1, dout);
    k_agg<<<2048, 256, 0, stream>>>(src, dst, deg, out1, dout);
}

// Round 2
// 277.831 us; speedup vs baseline: 5.4290x; 5.4290x over previous
//
#include <hip/hip_runtime.h>

#define N_NODES 50000
#define N_EDGES 800000
#define IN_DIM  128
#define HID_DIM 64
#define OUT_DIM 64
#define NB_NODE ((N_NODES + 255) / 256)   // 196 blocks over nodes

// ---------------- CSR build: histogram of dst ----------------
__global__ void k_zero_counts(int* __restrict__ counts) {
    int i = blockIdx.x * blockDim.x + threadIdx.x;
    if (i < N_NODES) counts[i] = 0;
}

__global__ void k_count(const int* __restrict__ dst, int* __restrict__ counts) {
    int tid = blockIdx.x * blockDim.x + threadIdx.x;
    int stride = gridDim.x * blockDim.x;
    for (int e = tid; e < N_EDGES; e += stride)
        atomicAdd(&counts[dst[e]], 1);
}

// per-256-block exclusive scan + block totals
__global__ void k_scan_local(const int* __restrict__ counts, int* __restrict__ ex,
                             int* __restrict__ bsum) {
    __shared__ int s[256];
    const int t = threadIdx.x;
    const int i = blockIdx.x * 256 + t;
    int v = (i < N_NODES) ? counts[i] : 0;
    s[t] = v;
    __syncthreads();
    for (int off = 1; off < 256; off <<= 1) {
        int add = (t >= off) ? s[t - off] : 0;
        __syncthreads();
        s[t] += add;
        __syncthreads();
    }
    ex[i < N_NODES ? i : 0] = (i < N_NODES) ? (s[t] - v) : ex[0];  // guarded below anyway
    if (i < N_NODES) ex[i] = s[t] - v;
    if (t == 255) bsum[blockIdx.x] = s[255];
}

// single-block exclusive scan of the 196 block sums
__global__ void k_scan_bsum(int* __restrict__ bsum) {
    __shared__ int s[256];
    const int t = threadIdx.x;
    int v = (t < NB_NODE) ? bsum[t] : 0;
    s[t] = v;
    __syncthreads();
    for (int off = 1; off < 256; off <<= 1) {
        int add = (t >= off) ? s[t - off] : 0;
        __syncthreads();
        s[t] += add;
        __syncthreads();
    }
    if (t < NB_NODE) bsum[t] = s[t] - v;  // exclusive
}

// offsets = ex + bsum[block]; cursor = offsets; dinv = rsqrt(count+1)
__global__ void k_finalize(const int* __restrict__ counts, const int* __restrict__ ex,
                           const int* __restrict__ bsum, int* __restrict__ offsets,
                           int* __restrict__ cursor, float* __restrict__ dinv) {
    int i = blockIdx.x * blockDim.x + threadIdx.x;
    if (i >= N_NODES) return;
    int o = ex[i] + bsum[blockIdx.x];
    offsets[i] = o;
    cursor[i] = o;
    dinv[i] = rsqrtf((float)(counts[i] + 1));  // +1: self-loop
}

__global__ void k_scatter(const int* __restrict__ src, const int* __restrict__ dst,
                          int* __restrict__ cursor, int* __restrict__ csr) {
    int tid = blockIdx.x * blockDim.x + threadIdx.x;
    int stride = gridDim.x * blockDim.x;
    for (int e = tid; e < N_EDGES; e += stride) {
        int d = dst[e];
        int pos = atomicAdd(&cursor[d], 1);
        csr[pos] = src[e];
    }
}

// ---------------- GEMM1: h1s = (x @ W1) * dinv[n]  (pre-scaled rows) ----------------
__global__ __launch_bounds__(256) void k_gemm1(
        const float* __restrict__ x, const float* __restrict__ W1,
        const float* __restrict__ dinv, float* __restrict__ h1s) {
    __shared__ float xs[4][IN_DIM];
    const int wave = threadIdx.x >> 6;
    const int lane = threadIdx.x & 63;
    const int n = blockIdx.x * 4 + wave;
    if (n < N_NODES) {
        xs[wave][lane]      = x[(long)n * IN_DIM + lane];
        xs[wave][lane + 64] = x[(long)n * IN_DIM + lane + 64];
    }
    __syncthreads();
    if (n >= N_NODES) return;
    float acc = 0.0f;
#pragma unroll 8
    for (int k = 0; k < IN_DIM; ++k)
        acc = fmaf(xs[wave][k], W1[k * HID_DIM + lane], acc);
    h1s[(long)n * HID_DIM + lane] = acc * dinv[n];
}

// ---------------- CSR aggregation: out[n] = (hs[n] + sum_{s in N(n)} hs[s]) * dinv[n] + b
__global__ __launch_bounds__(256) void k_agg_csr(
        const int* __restrict__ csr, const int* __restrict__ offsets,
        const int* __restrict__ counts, const float* __restrict__ dinv,
        const float* __restrict__ hs, const float* __restrict__ bias,
        float* __restrict__ out) {
    const int wave = threadIdx.x >> 6;
    const int lane = threadIdx.x & 63;
    const int n = blockIdx.x * 4 + wave;
    if (n >= N_NODES) return;
    const int beg = offsets[n];
    const int cnt = counts[n];
    float acc0 = hs[(long)n * 64 + lane];  // self-loop (rows pre-scaled by dinv[src])
    float acc1 = 0.0f;
    int e = 0;
    for (; e + 2 <= cnt; e += 2) {
        const int s0 = csr[beg + e];
        const int s1 = csr[beg + e + 1];
        acc0 += hs[(long)s0 * 64 + lane];
        acc1 += hs[(long)s1 * 64 + lane];
    }
    if (e < cnt)
        acc1 += hs[(long)csr[beg + e] * 64 + lane];
    out[(long)n * 64 + lane] = (acc0 + acc1) * dinv[n] + bias[lane];
}

// ---------------- GEMM2: h3s = (relu(out1) @ W2) * dinv[n]  (writes over h1s) --------
__global__ __launch_bounds__(256) void k_gemm2(
        const float* __restrict__ out1, const float* __restrict__ W2,
        const float* __restrict__ dinv, float* __restrict__ h3s) {
    __shared__ float hs[4][HID_DIM];
    const int wave = threadIdx.x >> 6;
    const int lane = threadIdx.x & 63;
    const int n = blockIdx.x * 4 + wave;
    if (n < N_NODES)
        hs[wave][lane] = fmaxf(out1[(long)n * HID_DIM + lane], 0.0f);
    __syncthreads();
    if (n >= N_NODES) return;
    float acc = 0.0f;
#pragma unroll 8
    for (int k = 0; k < HID_DIM; ++k)
        acc = fmaf(hs[wave][k], W2[k * OUT_DIM + lane], acc);
    h3s[(long)n * HID_DIM + lane] = acc * dinv[n];
}

extern "C" void kernel_launch(void* const* d_in, const int* in_sizes, int n_in,
                              void* d_out, int out_size, void* d_ws, size_t ws_size,
                              hipStream_t stream) {
    const float* x  = (const float*)d_in[0];
    const int*   ei = (const int*)d_in[1];          // [2, N_EDGES] (int32 from harness)
    const float* W1 = (const float*)d_in[2];
    const float* b1 = (const float*)d_in[3];
    const float* W2 = (const float*)d_in[4];
    const float* b2 = (const float*)d_in[5];
    float* dout = (float*)d_out;

    const int* src = ei;
    const int* dst = ei + N_EDGES;

    // workspace layout (all 4-byte elems)
    char* w = (char*)d_ws;
    int*   counts  = (int*)w;                 w += 50176 * 4;   // N padded to 256
    int*   ex      = (int*)w;                 w += 50176 * 4;
    int*   bsum    = (int*)w;                 w += 256 * 4;
    int*   offsets = (int*)w;                 w += 50176 * 4;
    int*   cursor  = (int*)w;                 w += 50176 * 4;
    float* dinv    = (float*)w;               w += 50176 * 4;
    int*   csr     = (int*)w;                 w += (long)N_EDGES * 4;
    float* h1s     = (float*)w;               w += (long)N_NODES * 64 * 4;  // also h3s
    float* out1    = (float*)w;

    const int nbN = NB_NODE;          // 196
    const int nbE = (N_EDGES + 255) / 256;  // 3125
    const int nbG = (N_NODES + 3) / 4;      // 12500

    // CSR build + degrees
    k_zero_counts<<<nbN, 256, 0, stream>>>(counts);
    k_count<<<nbE, 256, 0, stream>>>(dst, counts);
    k_scan_local<<<nbN, 256, 0, stream>>>(counts, ex, bsum);
    k_scan_bsum<<<1, 256, 0, stream>>>(bsum);
    k_finalize<<<nbN, 256, 0, stream>>>(counts, ex, bsum, offsets, cursor, dinv);
    k_scatter<<<nbE, 256, 0, stream>>>(src, dst, cursor, csr);

    // layer 1
    k_gemm1<<<nbG, 256, 0, stream>>>(x, W1, dinv, h1s);
    k_agg_csr<<<nbG, 256, 0, stream>>>(csr, offsets, counts, dinv, h1s, b1, out1);
    // layer 2
    k_gemm2<<<nbG, 256, 0, stream>>>(out1, W2, dinv, h1s);
    k_agg_csr<<<nbG, 256, 0, stream>>>(csr, offsets, counts, dinv, h1s, b2, dout);
}

// Round 3
// 222.472 us; speedup vs baseline: 6.7799x; 1.2488x over previous
//
#include <hip/hip_runtime.h>

#define N_NODES 50000
#define N_EDGES 800000
#define IN_DIM  128
#define HID_DIM 64
#define OUT_DIM 64
#define NB_NODE ((N_NODES + 255) / 256)   // 196 blocks over nodes

// ---------------- CSR build: histogram of dst ----------------
__global__ void k_zero_counts(int* __restrict__ counts) {
    int i = blockIdx.x * blockDim.x + threadIdx.x;
    if (i < N_NODES) counts[i] = 0;
}

__global__ void k_count(const int* __restrict__ dst, int* __restrict__ counts) {
    int e = blockIdx.x * blockDim.x + threadIdx.x;
    if (e < N_EDGES) atomicAdd(&counts[dst[e]], 1);
}

// per-256-block exclusive scan + block totals
__global__ void k_scan_local(const int* __restrict__ counts, int* __restrict__ ex,
                             int* __restrict__ bsum) {
    __shared__ int s[256];
    const int t = threadIdx.x;
    const int i = blockIdx.x * 256 + t;
    int v = (i < N_NODES) ? counts[i] : 0;
    s[t] = v;
    __syncthreads();
    for (int off = 1; off < 256; off <<= 1) {
        int add = (t >= off) ? s[t - off] : 0;
        __syncthreads();
        s[t] += add;
        __syncthreads();
    }
    if (i < N_NODES) ex[i] = s[t] - v;
    if (t == 255) bsum[blockIdx.x] = s[255];
}

// single-block exclusive scan of the 196 block sums
__global__ void k_scan_bsum(int* __restrict__ bsum) {
    __shared__ int s[256];
    const int t = threadIdx.x;
    int v = (t < NB_NODE) ? bsum[t] : 0;
    s[t] = v;
    __syncthreads();
    for (int off = 1; off < 256; off <<= 1) {
        int add = (t >= off) ? s[t - off] : 0;
        __syncthreads();
        s[t] += add;
        __syncthreads();
    }
    if (t < NB_NODE) bsum[t] = s[t] - v;  // exclusive
}

// offsets = ex + bsum[block]; cursor = offsets; dinv = rsqrt(count+1)
__global__ void k_finalize(const int* __restrict__ counts, const int* __restrict__ ex,
                           const int* __restrict__ bsum, int* __restrict__ offsets,
                           int* __restrict__ cursor, float* __restrict__ dinv) {
    int i = blockIdx.x * blockDim.x + threadIdx.x;
    if (i >= N_NODES) return;
    int o = ex[i] + bsum[blockIdx.x];
    offsets[i] = o;
    cursor[i] = o;
    dinv[i] = rsqrtf((float)(counts[i] + 1));  // +1: self-loop
}

__global__ void k_scatter(const int* __restrict__ src, const int* __restrict__ dst,
                          int* __restrict__ cursor, int* __restrict__ csr) {
    int e = blockIdx.x * blockDim.x + threadIdx.x;
    if (e >= N_EDGES) return;
    int d = dst[e];
    int pos = atomicAdd(&cursor[d], 1);
    csr[pos] = src[e];
}

// ---------------- GEMM1: h1s = (x @ W1) * dinv[n] ; 8 nodes/block, 2 nodes/thread ----
__global__ __launch_bounds__(256) void k_gemm1(
        const float* __restrict__ x, const float* __restrict__ W1,
        const float* __restrict__ dinv, float* __restrict__ h1s) {
    __shared__ float xs[8][IN_DIM];
    const int t = threadIdx.x;
    const int wave = t >> 6;
    const int lane = t & 63;
    const long base = (long)blockIdx.x * 8;  // 50000 % 8 == 0 -> no bounds checks
    // stage 8 rows of x (4 KB) with one float4 per thread
    reinterpret_cast<float4*>(&xs[0][0])[t] =
        reinterpret_cast<const float4*>(&x[base * IN_DIM])[t];
    __syncthreads();
    const int n0 = wave * 2;        // local node ids
    const int n1 = wave * 2 + 1;
    float acc0 = 0.0f, acc1 = 0.0f;
#pragma unroll 8
    for (int k = 0; k < IN_DIM; ++k) {
        const float wv = W1[k * HID_DIM + lane];
        acc0 = fmaf(xs[n0][k], wv, acc0);
        acc1 = fmaf(xs[n1][k], wv, acc1);
    }
    h1s[(base + n0) * HID_DIM + lane] = acc0 * dinv[base + n0];
    h1s[(base + n1) * HID_DIM + lane] = acc1 * dinv[base + n1];
}

// ---------------- fused: agg layer1 + bias + ReLU + GEMM2 + pre-scale ---------------
// out1row = (h1s[n] + sum_neighbors h1s[s]) * dinv[n] + b1   (held across 64 lanes)
// h3s[n]  = (relu(out1row) @ W2) * dinv[n]
__global__ __launch_bounds__(256) void k_agg1_fused(
        const int* __restrict__ csr, const int* __restrict__ offsets,
        const int* __restrict__ counts, const float* __restrict__ dinv,
        const float* __restrict__ h1s, const float* __restrict__ b1,
        const float* __restrict__ W2, float* __restrict__ h3s) {
    __shared__ float rs[4][HID_DIM];
    const int wave = threadIdx.x >> 6;
    const int lane = threadIdx.x & 63;
    const int n = blockIdx.x * 4 + wave;   // 50000 % 4 == 0
    const int beg = offsets[n];
    const int cnt = counts[n];
    float a0 = h1s[(long)n * 64 + lane];   // self-loop (rows pre-scaled by dinv[src])
    float a1 = 0.0f, a2 = 0.0f, a3 = 0.0f;
    int e = 0;
    for (; e + 4 <= cnt; e += 4) {
        const int s0 = csr[beg + e];
        const int s1 = csr[beg + e + 1];
        const int s2 = csr[beg + e + 2];
        const int s3 = csr[beg + e + 3];
        a0 += h1s[(long)s0 * 64 + lane];
        a1 += h1s[(long)s1 * 64 + lane];
        a2 += h1s[(long)s2 * 64 + lane];
        a3 += h1s[(long)s3 * 64 + lane];
    }
    for (; e < cnt; ++e)
        a1 += h1s[(long)csr[beg + e] * 64 + lane];
    const float di = dinv[n];
    const float row = ((a0 + a2) + (a1 + a3)) * di + b1[lane];
    rs[wave][lane] = fmaxf(row, 0.0f);
    __syncthreads();
    float acc = 0.0f;
#pragma unroll 8
    for (int k = 0; k < HID_DIM; ++k)
        acc = fmaf(rs[wave][k], W2[k * OUT_DIM + lane], acc);
    h3s[(long)n * 64 + lane] = acc * di;
}

// ---------------- final aggregation: dout = (h3s[n] + sum h3s[s]) * dinv[n] + b2 ----
__global__ __launch_bounds__(256) void k_agg2(
        const int* __restrict__ csr, const int* __restrict__ offsets,
        const int* __restrict__ counts, const float* __restrict__ dinv,
        const float* __restrict__ h3s, const float* __restrict__ b2,
        float* __restrict__ dout) {
    const int wave = threadIdx.x >> 6;
    const int lane = threadIdx.x & 63;
    const int n = blockIdx.x * 4 + wave;
    const int beg = offsets[n];
    const int cnt = counts[n];
    float a0 = h3s[(long)n * 64 + lane];
    float a1 = 0.0f, a2 = 0.0f, a3 = 0.0f;
    int e = 0;
    for (; e + 4 <= cnt; e += 4) {
        const int s0 = csr[beg + e];
        const int s1 = csr[beg + e + 1];
        const int s2 = csr[beg + e + 2];
        const int s3 = csr[beg + e + 3];
        a0 += h3s[(long)s0 * 64 + lane];
        a1 += h3s[(long)s1 * 64 + lane];
        a2 += h3s[(long)s2 * 64 + lane];
        a3 += h3s[(long)s3 * 64 + lane];
    }
    for (; e < cnt; ++e)
        a1 += h3s[(long)csr[beg + e] * 64 + lane];
    dout[(long)n * 64 + lane] = ((a0 + a2) + (a1 + a3)) * dinv[n] + b2[lane];
}

extern "C" void kernel_launch(void* const* d_in, const int* in_sizes, int n_in,
                              void* d_out, int out_size, void* d_ws, size_t ws_size,
                              hipStream_t stream) {
    const float* x  = (const float*)d_in[0];
    const int*   ei = (const int*)d_in[1];          // [2, N_EDGES]
    const float* W1 = (const float*)d_in[2];
    const float* b1 = (const float*)d_in[3];
    const float* W2 = (const float*)d_in[4];
    const float* b2 = (const float*)d_in[5];
    float* dout = (float*)d_out;

    const int* src = ei;
    const int* dst = ei + N_EDGES;

    char* w = (char*)d_ws;
    int*   counts  = (int*)w;                 w += 50176 * 4;
    int*   ex      = (int*)w;                 w += 50176 * 4;
    int*   bsum    = (int*)w;                 w += 256 * 4;
    int*   offsets = (int*)w;                 w += 50176 * 4;
    int*   cursor  = (int*)w;                 w += 50176 * 4;
    float* dinv    = (float*)w;               w += 50176 * 4;
    int*   csr     = (int*)w;                 w += (long)N_EDGES * 4;
    float* h1s     = (float*)w;               w += (long)N_NODES * 64 * 4;
    float* h3s     = (float*)w;

    const int nbN = NB_NODE;                 // 196
    const int nbE = (N_EDGES + 255) / 256;   // 3125

    k_zero_counts<<<nbN, 256, 0, stream>>>(counts);
    k_count<<<nbE, 256, 0, stream>>>(dst, counts);
    k_scan_local<<<nbN, 256, 0, stream>>>(counts, ex, bsum);
    k_scan_bsum<<<1, 256, 0, stream>>>(bsum);
    k_finalize<<<nbN, 256, 0, stream>>>(counts, ex, bsum, offsets, cursor, dinv);
    k_scatter<<<nbE, 256, 0, stream>>>(src, dst, cursor, csr);

    k_gemm1<<<N_NODES / 8, 256, 0, stream>>>(x, W1, dinv, h1s);
    k_agg1_fused<<<N_NODES / 4, 256, 0, stream>>>(csr, offsets, counts, dinv, h1s, b1, W2, h3s);
    k_agg2<<<N_NODES / 4, 256, 0, stream>>>(csr, offsets, counts, dinv, h3s, b2, dout);
}

// Round 4
// 212.611 us; speedup vs baseline: 7.0944x; 1.0464x over previous
//
#include <hip/hip_runtime.h>

#define N_NODES 50000
#define N_EDGES 800000
#define IN_DIM  128
#define HID_DIM 64
#define OUT_DIM 64
#define NB_NODE ((N_NODES + 255) / 256)   // 196 blocks over nodes

__device__ __forceinline__ void f4add(float4& a, const float4 b) {
    a.x += b.x; a.y += b.y; a.z += b.z; a.w += b.w;
}

// ---------------- CSR build ----------------
__global__ void k_zero_counts(int* __restrict__ counts) {
    int i = blockIdx.x * blockDim.x + threadIdx.x;
    if (i < N_NODES) counts[i] = 0;
}

__global__ void k_count(const int* __restrict__ dst, int* __restrict__ counts) {
    int e = blockIdx.x * blockDim.x + threadIdx.x;
    if (e < N_EDGES) atomicAdd(&counts[dst[e]], 1);
}

__global__ void k_scan_local(const int* __restrict__ counts, int* __restrict__ ex,
                             int* __restrict__ bsum) {
    __shared__ int s[256];
    const int t = threadIdx.x;
    const int i = blockIdx.x * 256 + t;
    int v = (i < N_NODES) ? counts[i] : 0;
    s[t] = v;
    __syncthreads();
    for (int off = 1; off < 256; off <<= 1) {
        int add = (t >= off) ? s[t - off] : 0;
        __syncthreads();
        s[t] += add;
        __syncthreads();
    }
    if (i < N_NODES) ex[i] = s[t] - v;
    if (t == 255) bsum[blockIdx.x] = s[255];
}

__global__ void k_scan_bsum(int* __restrict__ bsum) {
    __shared__ int s[256];
    const int t = threadIdx.x;
    int v = (t < NB_NODE) ? bsum[t] : 0;
    s[t] = v;
    __syncthreads();
    for (int off = 1; off < 256; off <<= 1) {
        int add = (t >= off) ? s[t - off] : 0;
        __syncthreads();
        s[t] += add;
        __syncthreads();
    }
    if (t < NB_NODE) bsum[t] = s[t] - v;  // exclusive
}

__global__ void k_finalize(const int* __restrict__ counts, const int* __restrict__ ex,
                           const int* __restrict__ bsum, int* __restrict__ offsets,
                           int* __restrict__ cursor, float* __restrict__ dinv) {
    int i = blockIdx.x * blockDim.x + threadIdx.x;
    if (i >= N_NODES) return;
    int o = ex[i] + bsum[blockIdx.x];
    offsets[i] = o;
    cursor[i] = o;
    dinv[i] = rsqrtf((float)(counts[i] + 1));  // +1: self-loop
}

__global__ void k_scatter(const int* __restrict__ src, const int* __restrict__ dst,
                          int* __restrict__ cursor, int* __restrict__ csr) {
    int e = blockIdx.x * blockDim.x + threadIdx.x;
    if (e >= N_EDGES) return;
    int d = dst[e];
    int pos = atomicAdd(&cursor[d], 1);
    csr[pos] = src[e];
}

// ---------------- GEMM1: h1s = (x @ W1) * dinv[n] ; 8 nodes/block, 2 nodes/thread ----
__global__ __launch_bounds__(256) void k_gemm1(
        const float* __restrict__ x, const float* __restrict__ W1,
        const float* __restrict__ dinv, float* __restrict__ h1s) {
    __shared__ float xs[8][IN_DIM];
    const int t = threadIdx.x;
    const int wave = t >> 6;
    const int lane = t & 63;
    const long base = (long)blockIdx.x * 8;  // 50000 % 8 == 0
    reinterpret_cast<float4*>(&xs[0][0])[t] =
        reinterpret_cast<const float4*>(&x[base * IN_DIM])[t];
    __syncthreads();
    const int n0 = wave * 2;
    const int n1 = wave * 2 + 1;
    float acc0 = 0.0f, acc1 = 0.0f;
#pragma unroll 8
    for (int k = 0; k < IN_DIM; ++k) {
        const float wv = W1[k * HID_DIM + lane];
        acc0 = fmaf(xs[n0][k], wv, acc0);
        acc1 = fmaf(xs[n1][k], wv, acc1);
    }
    h1s[(base + n0) * HID_DIM + lane] = acc0 * dinv[base + n0];
    h1s[(base + n1) * HID_DIM + lane] = acc1 * dinv[base + n1];
}

// ---------------- shared gather core: 16 lanes/row float4, 4 edge-groups/wave --------
// Returns the wave-wide reduced row chunk (all lanes hold it; lanes 0-15 = sub chunks).
__device__ __forceinline__ float4 gather_rows(
        const int* __restrict__ csr, const float* __restrict__ h,
        int n, int beg, int cnt, int grp, int sub) {
    float4 a0 = {0,0,0,0}, a1 = {0,0,0,0}, a2 = {0,0,0,0}, a3 = {0,0,0,0};
    int e = grp;
    for (; e + 12 < cnt; e += 16) {
        const int s0 = csr[beg + e];
        const int s1 = csr[beg + e + 4];
        const int s2 = csr[beg + e + 8];
        const int s3 = csr[beg + e + 12];
        f4add(a0, *reinterpret_cast<const float4*>(&h[(long)s0 * 64 + sub * 4]));
        f4add(a1, *reinterpret_cast<const float4*>(&h[(long)s1 * 64 + sub * 4]));
        f4add(a2, *reinterpret_cast<const float4*>(&h[(long)s2 * 64 + sub * 4]));
        f4add(a3, *reinterpret_cast<const float4*>(&h[(long)s3 * 64 + sub * 4]));
    }
    for (; e < cnt; e += 4)
        f4add(a0, *reinterpret_cast<const float4*>(&h[(long)csr[beg + e] * 64 + sub * 4]));
    if (grp == 0)  // self-loop row
        f4add(a1, *reinterpret_cast<const float4*>(&h[(long)n * 64 + sub * 4]));
    float4 a;
    a.x = (a0.x + a1.x) + (a2.x + a3.x);
    a.y = (a0.y + a1.y) + (a2.y + a3.y);
    a.z = (a0.z + a1.z) + (a2.z + a3.z);
    a.w = (a0.w + a1.w) + (a2.w + a3.w);
    // reduce across the 4 groups (lanes l, l^16, l^32, l^48)
    a.x += __shfl_xor(a.x, 16); a.x += __shfl_xor(a.x, 32);
    a.y += __shfl_xor(a.y, 16); a.y += __shfl_xor(a.y, 32);
    a.z += __shfl_xor(a.z, 16); a.z += __shfl_xor(a.z, 32);
    a.w += __shfl_xor(a.w, 16); a.w += __shfl_xor(a.w, 32);
    return a;
}

// ---------------- fused: agg layer1 + bias + ReLU + GEMM2 + pre-scale ---------------
__global__ __launch_bounds__(256) void k_agg1_fused(
        const int* __restrict__ csr, const int* __restrict__ offsets,
        const int* __restrict__ counts, const float* __restrict__ dinv,
        const float* __restrict__ h1s, const float* __restrict__ b1,
        const float* __restrict__ W2, float* __restrict__ h3s) {
    __shared__ float rs[4][HID_DIM];
    const int wave = threadIdx.x >> 6;
    const int lane = threadIdx.x & 63;
    const int grp = lane >> 4;
    const int sub = lane & 15;
    const int n = blockIdx.x * 4 + wave;   // 50000 % 4 == 0
    const int beg = offsets[n];
    const int cnt = counts[n];
    float4 a = gather_rows(csr, h1s, n, beg, cnt, grp, sub);
    const float di = dinv[n];
    if (grp == 0) {
        const float4 bv = *reinterpret_cast<const float4*>(&b1[sub * 4]);
        float4 r;
        r.x = fmaxf(a.x * di + bv.x, 0.0f);
        r.y = fmaxf(a.y * di + bv.y, 0.0f);
        r.z = fmaxf(a.z * di + bv.z, 0.0f);
        r.w = fmaxf(a.w * di + bv.w, 0.0f);
        *reinterpret_cast<float4*>(&rs[wave][sub * 4]) = r;
    }
    __syncthreads();
    float acc = 0.0f;
#pragma unroll 8
    for (int k = 0; k < HID_DIM; ++k)
        acc = fmaf(rs[wave][k], W2[k * OUT_DIM + lane], acc);
    h3s[(long)n * 64 + lane] = acc * di;
}

// ---------------- final aggregation ----------------
__global__ __launch_bounds__(256) void k_agg2(
        const int* __restrict__ csr, const int* __restrict__ offsets,
        const int* __restrict__ counts, const float* __restrict__ dinv,
        const float* __restrict__ h3s, const float* __restrict__ b2,
        float* __restrict__ dout) {
    const int wave = threadIdx.x >> 6;
    const int lane = threadIdx.x & 63;
    const int grp = lane >> 4;
    const int sub = lane & 15;
    const int n = blockIdx.x * 4 + wave;
    const int beg = offsets[n];
    const int cnt = counts[n];
    float4 a = gather_rows(csr, h3s, n, beg, cnt, grp, sub);
    if (grp == 0) {
        const float di = dinv[n];
        const float4 bv = *reinterpret_cast<const float4*>(&b2[sub * 4]);
        float4 r;
        r.x = a.x * di + bv.x;
        r.y = a.y * di + bv.y;
        r.z = a.z * di + bv.z;
        r.w = a.w * di + bv.w;
        *reinterpret_cast<float4*>(&dout[(long)n * 64 + sub * 4]) = r;
    }
}

extern "C" void kernel_launch(void* const* d_in, const int* in_sizes, int n_in,
                              void* d_out, int out_size, void* d_ws, size_t ws_size,
                              hipStream_t stream) {
    const float* x  = (const float*)d_in[0];
    const int*   ei = (const int*)d_in[1];          // [2, N_EDGES]
    const float* W1 = (const float*)d_in[2];
    const float* b1 = (const float*)d_in[3];
    const float* W2 = (const float*)d_in[4];
    const float* b2 = (const float*)d_in[5];
    float* dout = (float*)d_out;

    const int* src = ei;
    const int* dst = ei + N_EDGES;

    char* w = (char*)d_ws;
    int*   counts  = (int*)w;                 w += 50176 * 4;
    int*   ex      = (int*)w;                 w += 50176 * 4;
    int*   bsum    = (int*)w;                 w += 256 * 4;
    int*   offsets = (int*)w;                 w += 50176 * 4;
    int*   cursor  = (int*)w;                 w += 50176 * 4;
    float* dinv    = (float*)w;               w += 50176 * 4;
    int*   csr     = (int*)w;                 w += (long)N_EDGES * 4;
    float* h1s     = (float*)w;               w += (long)N_NODES * 64 * 4;
    float* h3s     = (float*)w;

    const int nbN = NB_NODE;                 // 196
    const int nbE = (N_EDGES + 255) / 256;   // 3125

    k_zero_counts<<<nbN, 256, 0, stream>>>(counts);
    k_count<<<nbE, 256, 0, stream>>>(dst, counts);
    k_scan_local<<<nbN, 256, 0, stream>>>(counts, ex, bsum);
    k_scan_bsum<<<1, 256, 0, stream>>>(bsum);
    k_finalize<<<nbN, 256, 0, stream>>>(counts, ex, bsum, offsets, cursor, dinv);
    k_scatter<<<nbE, 256, 0, stream>>>(src, dst, cursor, csr);

    k_gemm1<<<N_NODES / 8, 256, 0, stream>>>(x, W1, dinv, h1s);
    k_agg1_fused<<<N_NODES / 4, 256, 0, stream>>>(csr, offsets, counts, dinv, h1s, b1, W2, h3s);
    k_agg2<<<N_NODES / 4, 256, 0, stream>>>(csr, offsets, counts, dinv, h3s, b2, dout);
}

// Round 5
// 199.858 us; speedup vs baseline: 7.5471x; 1.0638x over previous
//
#include <hip/hip_runtime.h>

#define N_NODES 50000
#define N_EDGES 800000
#define IN_DIM  128
#define HID_DIM 64
#define OUT_DIM 64
#define NB_NODE ((N_NODES + 255) / 256)   // 196 blocks over nodes

typedef _Float16 half4v __attribute__((ext_vector_type(4)));

__device__ __forceinline__ void f4addh(float4& a, const half4v v) {
    a.x += (float)v.x; a.y += (float)v.y; a.z += (float)v.z; a.w += (float)v.w;
}

// ---------------- CSR build ----------------
__global__ void k_zero_counts(int* __restrict__ counts) {
    int i = blockIdx.x * blockDim.x + threadIdx.x;
    if (i < N_NODES) counts[i] = 0;
}

__global__ void k_count(const int* __restrict__ dst, int* __restrict__ counts) {
    int e = blockIdx.x * blockDim.x + threadIdx.x;
    if (e < N_EDGES) atomicAdd(&counts[dst[e]], 1);
}

__global__ void k_scan_local(const int* __restrict__ counts, int* __restrict__ ex,
                             int* __restrict__ bsum) {
    __shared__ int s[256];
    const int t = threadIdx.x;
    const int i = blockIdx.x * 256 + t;
    int v = (i < N_NODES) ? counts[i] : 0;
    s[t] = v;
    __syncthreads();
    for (int off = 1; off < 256; off <<= 1) {
        int add = (t >= off) ? s[t - off] : 0;
        __syncthreads();
        s[t] += add;
        __syncthreads();
    }
    if (i < N_NODES) ex[i] = s[t] - v;
    if (t == 255) bsum[blockIdx.x] = s[255];
}

__global__ void k_scan_bsum(int* __restrict__ bsum) {
    __shared__ int s[256];
    const int t = threadIdx.x;
    int v = (t < NB_NODE) ? bsum[t] : 0;
    s[t] = v;
    __syncthreads();
    for (int off = 1; off < 256; off <<= 1) {
        int add = (t >= off) ? s[t - off] : 0;
        __syncthreads();
        s[t] += add;
        __syncthreads();
    }
    if (t < NB_NODE) bsum[t] = s[t] - v;  // exclusive
}

__global__ void k_finalize(const int* __restrict__ counts, const int* __restrict__ ex,
                           const int* __restrict__ bsum, int* __restrict__ offsets,
                           int* __restrict__ cursor, float* __restrict__ dinv) {
    int i = blockIdx.x * blockDim.x + threadIdx.x;
    if (i >= N_NODES) return;
    int o = ex[i] + bsum[blockIdx.x];
    offsets[i] = o;
    cursor[i] = o;
    dinv[i] = rsqrtf((float)(counts[i] + 1));  // +1: self-loop
}

__global__ void k_scatter(const int* __restrict__ src, const int* __restrict__ dst,
                          int* __restrict__ cursor, int* __restrict__ csr) {
    int e = blockIdx.x * blockDim.x + threadIdx.x;
    if (e >= N_EDGES) return;
    int d = dst[e];
    int pos = atomicAdd(&cursor[d], 1);
    csr[pos] = src[e];
}

// ---------------- GEMM1: h1s = fp16((x @ W1) * dinv[n]) ; 16 nodes/block, 4/thread ---
__global__ __launch_bounds__(256) void k_gemm1(
        const float* __restrict__ x, const float* __restrict__ W1,
        const float* __restrict__ dinv, _Float16* __restrict__ h1s) {
    __shared__ float xs[16][IN_DIM];   // 8 KB
    const int t = threadIdx.x;
    const int wave = t >> 6;
    const int lane = t & 63;
    const long base = (long)blockIdx.x * 16;  // 50000 % 16 == 0
    {
        float4* xsv = reinterpret_cast<float4*>(&xs[0][0]);
        const float4* xv = reinterpret_cast<const float4*>(&x[base * IN_DIM]);
        xsv[t]       = xv[t];
        xsv[t + 256] = xv[t + 256];
    }
    __syncthreads();
    const int n0 = wave * 4, n1 = n0 + 1, n2 = n0 + 2, n3 = n0 + 3;
    float a0 = 0.f, a1 = 0.f, a2 = 0.f, a3 = 0.f;
#pragma unroll 8
    for (int k = 0; k < IN_DIM; ++k) {
        const float wv = W1[k * HID_DIM + lane];
        a0 = fmaf(xs[n0][k], wv, a0);
        a1 = fmaf(xs[n1][k], wv, a1);
        a2 = fmaf(xs[n2][k], wv, a2);
        a3 = fmaf(xs[n3][k], wv, a3);
    }
    h1s[(base + n0) * HID_DIM + lane] = (_Float16)(a0 * dinv[base + n0]);
    h1s[(base + n1) * HID_DIM + lane] = (_Float16)(a1 * dinv[base + n1]);
    h1s[(base + n2) * HID_DIM + lane] = (_Float16)(a2 * dinv[base + n2]);
    h1s[(base + n3) * HID_DIM + lane] = (_Float16)(a3 * dinv[base + n3]);
}

// ---------------- gather core: 16 lanes/row, 8B(half4)/lane, 4 edge-groups/wave ------
__device__ __forceinline__ float4 gather_rows(
        const int* __restrict__ csr, const _Float16* __restrict__ h,
        int n, int beg, int cnt, int grp, int sub) {
    float4 a0 = {0,0,0,0}, a1 = {0,0,0,0}, a2 = {0,0,0,0}, a3 = {0,0,0,0};
    int e = grp;
    for (; e + 12 < cnt; e += 16) {
        const int s0 = csr[beg + e];
        const int s1 = csr[beg + e + 4];
        const int s2 = csr[beg + e + 8];
        const int s3 = csr[beg + e + 12];
        f4addh(a0, *reinterpret_cast<const half4v*>(&h[(long)s0 * 64 + sub * 4]));
        f4addh(a1, *reinterpret_cast<const half4v*>(&h[(long)s1 * 64 + sub * 4]));
        f4addh(a2, *reinterpret_cast<const half4v*>(&h[(long)s2 * 64 + sub * 4]));
        f4addh(a3, *reinterpret_cast<const half4v*>(&h[(long)s3 * 64 + sub * 4]));
    }
    for (; e < cnt; e += 4)
        f4addh(a0, *reinterpret_cast<const half4v*>(&h[(long)csr[beg + e] * 64 + sub * 4]));
    if (grp == 0)  // self-loop row
        f4addh(a1, *reinterpret_cast<const half4v*>(&h[(long)n * 64 + sub * 4]));
    float4 a;
    a.x = (a0.x + a1.x) + (a2.x + a3.x);
    a.y = (a0.y + a1.y) + (a2.y + a3.y);
    a.z = (a0.z + a1.z) + (a2.z + a3.z);
    a.w = (a0.w + a1.w) + (a2.w + a3.w);
    a.x += __shfl_xor(a.x, 16); a.x += __shfl_xor(a.x, 32);
    a.y += __shfl_xor(a.y, 16); a.y += __shfl_xor(a.y, 32);
    a.z += __shfl_xor(a.z, 16); a.z += __shfl_xor(a.z, 32);
    a.w += __shfl_xor(a.w, 16); a.w += __shfl_xor(a.w, 32);
    return a;
}

// ---------------- fused: agg layer1 + bias + ReLU + GEMM2 + pre-scale ---------------
__global__ __launch_bounds__(256) void k_agg1_fused(
        const int* __restrict__ csr, const int* __restrict__ offsets,
        const int* __restrict__ counts, const float* __restrict__ dinv,
        const _Float16* __restrict__ h1s, const float* __restrict__ b1,
        const float* __restrict__ W2, _Float16* __restrict__ h3s) {
    __shared__ float rs[4][HID_DIM];
    const int wave = threadIdx.x >> 6;
    const int lane = threadIdx.x & 63;
    const int grp = lane >> 4;
    const int sub = lane & 15;
    const int n = blockIdx.x * 4 + wave;   // 50000 % 4 == 0
    const int beg = offsets[n];
    const int cnt = counts[n];
    float4 a = gather_rows(csr, h1s, n, beg, cnt, grp, sub);
    const float di = dinv[n];
    if (grp == 0) {
        const float4 bv = *reinterpret_cast<const float4*>(&b1[sub * 4]);
        float4 r;
        r.x = fmaxf(a.x * di + bv.x, 0.0f);
        r.y = fmaxf(a.y * di + bv.y, 0.0f);
        r.z = fmaxf(a.z * di + bv.z, 0.0f);
        r.w = fmaxf(a.w * di + bv.w, 0.0f);
        *reinterpret_cast<float4*>(&rs[wave][sub * 4]) = r;
    }
    __syncthreads();
    float acc = 0.0f;
#pragma unroll 8
    for (int k = 0; k < HID_DIM; ++k)
        acc = fmaf(rs[wave][k], W2[k * OUT_DIM + lane], acc);
    h3s[(long)n * 64 + lane] = (_Float16)(acc * di);
}

// ---------------- final aggregation ----------------
__global__ __launch_bounds__(256) void k_agg2(
        const int* __restrict__ csr, const int* __restrict__ offsets,
        const int* __restrict__ counts, const float* __restrict__ dinv,
        const _Float16* __restrict__ h3s, const float* __restrict__ b2,
        float* __restrict__ dout) {
    const int wave = threadIdx.x >> 6;
    const int lane = threadIdx.x & 63;
    const int grp = lane >> 4;
    const int sub = lane & 15;
    const int n = blockIdx.x * 4 + wave;
    const int beg = offsets[n];
    const int cnt = counts[n];
    float4 a = gather_rows(csr, h3s, n, beg, cnt, grp, sub);
    if (grp == 0) {
        const float di = dinv[n];
        const float4 bv = *reinterpret_cast<const float4*>(&b2[sub * 4]);
        float4 r;
        r.x = a.x * di + bv.x;
        r.y = a.y * di + bv.y;
        r.z = a.z * di + bv.z;
        r.w = a.w * di + bv.w;
        *reinterpret_cast<float4*>(&dout[(long)n * 64 + sub * 4]) = r;
    }
}

extern "C" void kernel_launch(void* const* d_in, const int* in_sizes, int n_in,
                              void* d_out, int out_size, void* d_ws, size_t ws_size,
                              hipStream_t stream) {
    const float* x  = (const float*)d_in[0];
    const int*   ei = (const int*)d_in[1];          // [2, N_EDGES]
    const float* W1 = (const float*)d_in[2];
    const float* b1 = (const float*)d_in[3];
    const float* W2 = (const float*)d_in[4];
    const float* b2 = (const float*)d_in[5];
    float* dout = (float*)d_out;

    const int* src = ei;
    const int* dst = ei + N_EDGES;

    char* w = (char*)d_ws;
    int*      counts  = (int*)w;              w += 50176 * 4;
    int*      ex      = (int*)w;              w += 50176 * 4;
    int*      bsum    = (int*)w;              w += 256 * 4;
    int*      offsets = (int*)w;              w += 50176 * 4;
    int*      cursor  = (int*)w;              w += 50176 * 4;
    float*    dinv    = (float*)w;            w += 50176 * 4;
    int*      csr     = (int*)w;              w += (long)N_EDGES * 4;
    _Float16* h1s     = (_Float16*)w;         w += (long)N_NODES * 64 * 2;
    _Float16* h3s     = (_Float16*)w;

    const int nbN = NB_NODE;                 // 196
    const int nbE = (N_EDGES + 255) / 256;   // 3125

    k_zero_counts<<<nbN, 256, 0, stream>>>(counts);
    k_count<<<nbE, 256, 0, stream>>>(dst, counts);
    k_scan_local<<<nbN, 256, 0, stream>>>(counts, ex, bsum);
    k_scan_bsum<<<1, 256, 0, stream>>>(bsum);
    k_finalize<<<nbN, 256, 0, stream>>>(counts, ex, bsum, offsets, cursor, dinv);
    k_scatter<<<nbE, 256, 0, stream>>>(src, dst, cursor, csr);

    k_gemm1<<<N_NODES / 16, 256, 0, stream>>>(x, W1, dinv, h1s);
    k_agg1_fused<<<N_NODES / 4, 256, 0, stream>>>(csr, offsets, counts, dinv, h1s, b1, W2, h3s);
    k_agg2<<<N_NODES / 4, 256, 0, stream>>>(csr, offsets, counts, dinv, h3s, b2, dout);
}

// Round 6
// 153.225 us; speedup vs baseline: 9.8440x; 1.3043x over previous
//
#include <hip/hip_runtime.h>

#define N_NODES 50000
#define N_EDGES 800000
#define IN_DIM  128
#define HID_DIM 64
#define OUT_DIM 64
#define NB_NODE 196          // ceil(50000/256)
#define NSHARD 8
#define SHARD_SZ 6250        // 50000/8
#define SCAT_CHUNK 392
#define SCAT_BLOCKS (NSHARD * SCAT_CHUNK)   // 3136
#define GEMM1_BLOCKS 3125    // 50000/16
#define AGG_BLOCKS 3125      // 50000/16

typedef _Float16 half4v __attribute__((ext_vector_type(4)));

__device__ __forceinline__ void f4addh(float4& a, const half4v v) {
    a.x += (float)v.x; a.y += (float)v.y; a.z += (float)v.z; a.w += (float)v.w;
}

// ---------------- CSR build ----------------
__global__ void k_zero_counts(int* __restrict__ counts) {
    int i = blockIdx.x * blockDim.x + threadIdx.x;
    if (i < N_NODES) counts[i] = 0;
}

// sharded histogram: shard s only counts dst in [s*6250,(s+1)*6250)
__global__ void k_count(const int* __restrict__ dst, int* __restrict__ counts) {
    const int shard = blockIdx.x & 7;           // heuristic: bid%8 ~ XCD id
    const int chunk = blockIdx.x >> 3;
    const int lo = shard * SHARD_SZ, hi = lo + SHARD_SZ;
    for (int base = chunk * 256; base < N_EDGES; base += SCAT_CHUNK * 256) {
        const int e = base + threadIdx.x;
        if (e < N_EDGES) {
            const int d = dst[e];
            if (d >= lo && d < hi) atomicAdd(&counts[d], 1);
        }
    }
}

__global__ void k_scan_local(const int* __restrict__ counts, int* __restrict__ ex,
                             int* __restrict__ bsum) {
    __shared__ int s[256];
    const int t = threadIdx.x;
    const int i = blockIdx.x * 256 + t;
    int v = (i < N_NODES) ? counts[i] : 0;
    s[t] = v;
    __syncthreads();
    for (int off = 1; off < 256; off <<= 1) {
        int add = (t >= off) ? s[t - off] : 0;
        __syncthreads();
        s[t] += add;
        __syncthreads();
    }
    if (i < N_NODES) ex[i] = s[t] - v;
    if (t == 255) bsum[blockIdx.x] = s[255];
}

__global__ void k_scan_bsum(int* __restrict__ bsum) {
    __shared__ int s[256];
    const int t = threadIdx.x;
    int v = (t < NB_NODE) ? bsum[t] : 0;
    s[t] = v;
    __syncthreads();
    for (int off = 1; off < 256; off <<= 1) {
        int add = (t >= off) ? s[t - off] : 0;
        __syncthreads();
        s[t] += add;
        __syncthreads();
    }
    if (t < NB_NODE) bsum[t] = s[t] - v;  // exclusive
}

__global__ void k_finalize(const int* __restrict__ counts, const int* __restrict__ ex,
                           const int* __restrict__ bsum, int* __restrict__ offsets,
                           int* __restrict__ cursor, float* __restrict__ dinv) {
    int i = blockIdx.x * blockDim.x + threadIdx.x;
    if (i >= N_NODES) return;
    int o = ex[i] + bsum[blockIdx.x];
    offsets[i] = o;
    cursor[i] = o;
    dinv[i] = rsqrtf((float)(counts[i] + 1));  // +1: self-loop
}

// ---------------- fused: sharded scatter (blocks < SCAT_BLOCKS) || gemm1 ------------
// gemm1: h1s = fp16((x @ W1) * dinv[n]), 16 nodes/block, 4 nodes/thread
__global__ __launch_bounds__(256) void k_scatter_gemm1(
        const int* __restrict__ src, const int* __restrict__ dst,
        int* __restrict__ cursor, unsigned short* __restrict__ csr,
        const float* __restrict__ x, const float* __restrict__ W1,
        const float* __restrict__ dinv, _Float16* __restrict__ h1s) {
    __shared__ float xs[16][IN_DIM];   // 8 KB (used by gemm1 role only)
    const int bid = blockIdx.x;
    if (bid < SCAT_BLOCKS) {
        // ---- scatter role: shard by dst range, XCD-local csr/cursor lines ----
        const int shard = bid & 7;
        const int chunk = bid >> 3;
        const int lo = shard * SHARD_SZ, hi = lo + SHARD_SZ;
        for (int base = chunk * 256; base < N_EDGES; base += SCAT_CHUNK * 256) {
            const int e = base + threadIdx.x;
            if (e < N_EDGES) {
                const int d = dst[e];
                if (d >= lo && d < hi) {
                    const int pos = atomicAdd(&cursor[d], 1);
                    csr[pos] = (unsigned short)src[e];
                }
            }
        }
        return;
    }
    // ---- gemm1 role ----
    const int t = threadIdx.x;
    const int wave = t >> 6;
    const int lane = t & 63;
    const long base = (long)(bid - SCAT_BLOCKS) * 16;
    {
        float4* xsv = reinterpret_cast<float4*>(&xs[0][0]);
        const float4* xv = reinterpret_cast<const float4*>(&x[base * IN_DIM]);
        xsv[t]       = xv[t];
        xsv[t + 256] = xv[t + 256];
    }
    __syncthreads();
    const int n0 = wave * 4, n1 = n0 + 1, n2 = n0 + 2, n3 = n0 + 3;
    float a0 = 0.f, a1 = 0.f, a2 = 0.f, a3 = 0.f;
#pragma unroll 8
    for (int k = 0; k < IN_DIM; ++k) {
        const float wv = W1[k * HID_DIM + lane];
        a0 = fmaf(xs[n0][k], wv, a0);
        a1 = fmaf(xs[n1][k], wv, a1);
        a2 = fmaf(xs[n2][k], wv, a2);
        a3 = fmaf(xs[n3][k], wv, a3);
    }
    h1s[(base + n0) * HID_DIM + lane] = (_Float16)(a0 * dinv[base + n0]);
    h1s[(base + n1) * HID_DIM + lane] = (_Float16)(a1 * dinv[base + n1]);
    h1s[(base + n2) * HID_DIM + lane] = (_Float16)(a2 * dinv[base + n2]);
    h1s[(base + n3) * HID_DIM + lane] = (_Float16)(a3 * dinv[base + n3]);
}

// ---------------- gather core: one 16-lane group owns one node -----------------------
// Each lane holds a float4 slice (sub*4). 4-deep batched loads for MLP.
__device__ __forceinline__ float4 gather_node(
        const unsigned short* __restrict__ csr, const _Float16* __restrict__ h,
        int n, int beg, int cnt, int sub) {
    float4 a0 = {0,0,0,0}, a1 = {0,0,0,0}, a2 = {0,0,0,0}, a3 = {0,0,0,0};
    int e = 0;
    for (; e + 4 <= cnt; e += 4) {
        const int i0 = csr[beg + e];
        const int i1 = csr[beg + e + 1];
        const int i2 = csr[beg + e + 2];
        const int i3 = csr[beg + e + 3];
        const half4v v0 = *reinterpret_cast<const half4v*>(&h[(long)i0 * 64 + sub * 4]);
        const half4v v1 = *reinterpret_cast<const half4v*>(&h[(long)i1 * 64 + sub * 4]);
        const half4v v2 = *reinterpret_cast<const half4v*>(&h[(long)i2 * 64 + sub * 4]);
        const half4v v3 = *reinterpret_cast<const half4v*>(&h[(long)i3 * 64 + sub * 4]);
        f4addh(a0, v0); f4addh(a1, v1); f4addh(a2, v2); f4addh(a3, v3);
    }
    for (; e < cnt; ++e)
        f4addh(a0, *reinterpret_cast<const half4v*>(&h[(long)csr[beg + e] * 64 + sub * 4]));
    f4addh(a1, *reinterpret_cast<const half4v*>(&h[(long)n * 64 + sub * 4]));  // self-loop
    float4 a;
    a.x = (a0.x + a1.x) + (a2.x + a3.x);
    a.y = (a0.y + a1.y) + (a2.y + a3.y);
    a.z = (a0.z + a1.z) + (a2.z + a3.z);
    a.w = (a0.w + a1.w) + (a2.w + a3.w);
    return a;
}

// ---------------- fused: agg layer1 + bias + ReLU + GEMM2 + pre-scale ---------------
__global__ __launch_bounds__(256) void k_agg1_fused(
        const unsigned short* __restrict__ csr, const int* __restrict__ offsets,
        const int* __restrict__ counts, const float* __restrict__ dinv,
        const _Float16* __restrict__ h1s, const float* __restrict__ b1,
        const float* __restrict__ W2, _Float16* __restrict__ h3s) {
    __shared__ float rs[16][HID_DIM];   // 4 KB
    const int g = threadIdx.x >> 4;
    const int sub = threadIdx.x & 15;
    const long nbase = (long)blockIdx.x * 16;
    const int n = (int)nbase + g;
    const int beg = offsets[n];
    const int cnt = counts[n];
    float4 a = gather_node(csr, h1s, n, beg, cnt, sub);
    const float di = dinv[n];
    const float4 bv = *reinterpret_cast<const float4*>(&b1[sub * 4]);
    float4 r;
    r.x = fmaxf(a.x * di + bv.x, 0.0f);
    r.y = fmaxf(a.y * di + bv.y, 0.0f);
    r.z = fmaxf(a.z * di + bv.z, 0.0f);
    r.w = fmaxf(a.w * di + bv.w, 0.0f);
    *reinterpret_cast<float4*>(&rs[g][sub * 4]) = r;
    __syncthreads();
    // GEMM phase: wave w computes nodes 4w..4w+3
    const int wave = threadIdx.x >> 6;
    const int lane = threadIdx.x & 63;
    float acc[4] = {0.f, 0.f, 0.f, 0.f};
#pragma unroll 4
    for (int k = 0; k < HID_DIM; ++k) {
        const float wv = W2[k * OUT_DIM + lane];
#pragma unroll
        for (int m = 0; m < 4; ++m)
            acc[m] = fmaf(rs[wave * 4 + m][k], wv, acc[m]);
    }
#pragma unroll
    for (int m = 0; m < 4; ++m) {
        const long node = nbase + wave * 4 + m;
        h3s[node * 64 + lane] = (_Float16)(acc[m] * dinv[node]);
    }
}

// ---------------- final aggregation ----------------
__global__ __launch_bounds__(256) void k_agg2(
        const unsigned short* __restrict__ csr, const int* __restrict__ offsets,
        const int* __restrict__ counts, const float* __restrict__ dinv,
        const _Float16* __restrict__ h3s, const float* __restrict__ b2,
        float* __restrict__ dout) {
    const int g = threadIdx.x >> 4;
    const int sub = threadIdx.x & 15;
    const int n = blockIdx.x * 16 + g;
    const int beg = offsets[n];
    const int cnt = counts[n];
    float4 a = gather_node(csr, h3s, n, beg, cnt, sub);
    const float di = dinv[n];
    const float4 bv = *reinterpret_cast<const float4*>(&b2[sub * 4]);
    float4 r;
    r.x = a.x * di + bv.x;
    r.y = a.y * di + bv.y;
    r.z = a.z * di + bv.z;
    r.w = a.w * di + bv.w;
    *reinterpret_cast<float4*>(&dout[(long)n * 64 + sub * 4]) = r;
}

extern "C" void kernel_launch(void* const* d_in, const int* in_sizes, int n_in,
                              void* d_out, int out_size, void* d_ws, size_t ws_size,
                              hipStream_t stream) {
    const float* x  = (const float*)d_in[0];
    const int*   ei = (const int*)d_in[1];          // [2, N_EDGES]
    const float* W1 = (const float*)d_in[2];
    const float* b1 = (const float*)d_in[3];
    const float* W2 = (const float*)d_in[4];
    const float* b2 = (const float*)d_in[5];
    float* dout = (float*)d_out;

    const int* src = ei;
    const int* dst = ei + N_EDGES;

    char* w = (char*)d_ws;
    int*            counts  = (int*)w;          w += 50176 * 4;
    int*            ex      = (int*)w;          w += 50176 * 4;
    int*            bsum    = (int*)w;          w += 256 * 4;
    int*            offsets = (int*)w;          w += 50176 * 4;
    int*            cursor  = (int*)w;          w += 50176 * 4;
    float*          dinv    = (float*)w;        w += 50176 * 4;
    unsigned short* csr     = (unsigned short*)w; w += (long)N_EDGES * 2;
    _Float16*       h1s     = (_Float16*)w;     w += (long)N_NODES * 64 * 2;
    _Float16*       h3s     = (_Float16*)w;

    k_zero_counts<<<NB_NODE, 256, 0, stream>>>(counts);
    k_count<<<SCAT_BLOCKS, 256, 0, stream>>>(dst, counts);
    k_scan_local<<<NB_NODE, 256, 0, stream>>>(counts, ex, bsum);
    k_scan_bsum<<<1, 256, 0, stream>>>(bsum);
    k_finalize<<<NB_NODE, 256, 0, stream>>>(counts, ex, bsum, offsets, cursor, dinv);

    k_scatter_gemm1<<<SCAT_BLOCKS + GEMM1_BLOCKS, 256, 0, stream>>>(
        src, dst, cursor, csr, x, W1, dinv, h1s);

    k_agg1_fused<<<AGG_BLOCKS, 256, 0, stream>>>(csr, offsets, counts, dinv, h1s, b1, W2, h3s);
    k_agg2<<<AGG_BLOCKS, 256, 0, stream>>>(csr, offsets, counts, dinv, h3s, b2, dout);
}